// Round 6
// baseline (504.690 us; speedup 1.0000x reference)
//
#include <hip/hip_runtime.h>
#include <hip/hip_bf16.h>
#include <math.h>

#define N_NODES 100000
#define N_EDGES 1600000
#define F_IN 256
#define DIM 32
#define NC 40

#define NBLK 391            // ceil(100000/256)
#define NPARTS 16
#define PART_SZ 6250        // N_NODES / NPARTS

typedef _Float16 half_t;
union H8 { float4 f4; half_t h[8]; };

// ================= degree =================
__global__ void deg_kernel(const int* __restrict__ dst, int* __restrict__ degi) {
    int i = blockIdx.x * blockDim.x + threadIdx.x;
    if (i < N_EDGES) atomicAdd(&degi[dst[i]], 1);
}

// ================= deterministic prefix scan (3 phases) =================
// block-wide exclusive scan helper for blockDim<=512 (waves of 64)
__device__ __forceinline__ int block_scan_excl(int v, int& tot) {
    int lane = threadIdx.x & 63;
    int wid = threadIdx.x >> 6;
    int s = v;
#pragma unroll
    for (int off = 1; off < 64; off <<= 1) {
        int t = __shfl_up(s, off, 64);
        if (lane >= off) s += t;
    }
    __shared__ int wsum[8];
    if (lane == 63) wsum[wid] = s;
    __syncthreads();
    int nw = (blockDim.x + 63) >> 6;
    int wprev = 0, total = 0;
    for (int i = 0; i < nw; ++i) {
        int t = wsum[i];
        if (i < wid) wprev += t;
        total += t;
    }
    tot = total;
    return wprev + s - v;   // exclusive prefix
}

__global__ void scanA_kernel(const int* __restrict__ degi, int* __restrict__ partial) {
    int i = blockIdx.x * 256 + threadIdx.x;
    int v = (i < N_NODES) ? degi[i] : 0;
    int tot;
    block_scan_excl(v, tot);
    if (threadIdx.x == 0) partial[blockIdx.x] = tot;
}

__global__ void scanB_kernel(int* __restrict__ partial, int* __restrict__ blockoff) {
    int i = threadIdx.x;   // 512 threads
    int v = (i < NBLK) ? partial[i] : 0;
    int tot;
    int ex = block_scan_excl(v, tot);
    if (i < NBLK) blockoff[i] = ex;
}

__global__ void scanC_kernel(const int* __restrict__ degi,
                             const int* __restrict__ blockoff,
                             int* __restrict__ rowstart,
                             int* __restrict__ cursor) {
    int i = blockIdx.x * 256 + threadIdx.x;
    int v = (i < N_NODES) ? degi[i] : 0;
    int tot;
    int ex = block_scan_excl(v, tot) + blockoff[blockIdx.x];
    if (i < N_NODES) {
        rowstart[i] = ex;
        cursor[i] = ex;
    }
}

// ================= partition-phased fill =================
// Pass p touches only dst in [p*PART_SZ,(p+1)*PART_SZ): active csr write window
// ~400KB (node-ordered rowstart) + 25KB cursors -> L2-resident, writes coalesce.
__global__ void fill_part_kernel(const int* __restrict__ src,
                                 const int* __restrict__ dst,
                                 int* __restrict__ cursor,
                                 int* __restrict__ csr) {
    int tid = blockIdx.x * blockDim.x + threadIdx.x;
    int stride = gridDim.x * blockDim.x;
    int lo = 0;
    for (int p = 0; p < NPARTS; ++p) {
        int hi = (p == NPARTS - 1) ? N_NODES : lo + PART_SZ;
        for (int e = tid; e < N_EDGES; e += stride) {
            int d = dst[e];
            if (d >= lo && d < hi) {
                int pos = atomicAdd(&cursor[d], 1);
                csr[pos] = src[e];
            }
        }
        lo = hi;
    }
}

// ================= layer-1 projection (register-tiled GEMM) =================
#define PT_NODES 256
#define PT_KT 16

__global__ __launch_bounds__(256)
void proj1_tiled(const float* __restrict__ x,
                 const float* __restrict__ W1l,
                 const float* __restrict__ W1r,
                 half_t* __restrict__ P1h,
                 float* __restrict__ R1) {
    __shared__ float xs[PT_KT][PT_NODES];  // 16 KB
    __shared__ float ws[PT_KT][64];        // 4 KB
    int t = threadIdx.x;
    int ng = t >> 3;   // 0..31 node group
    int cg = t & 7;    // 0..7 col group
    int n0 = blockIdx.x * PT_NODES;

    float acc[8][8];
#pragma unroll
    for (int i = 0; i < 8; ++i)
#pragma unroll
        for (int j = 0; j < 8; ++j) acc[i][j] = 0.f;

    int ldnode = n0 + t; if (ldnode >= N_NODES) ldnode = N_NODES - 1;
    const float* xrow = x + (size_t)ldnode * F_IN;
    int wr = t >> 4;           // 0..15 (k within tile)
    int wc = (t & 15) * 4;     // 0..60

    for (int k0 = 0; k0 < F_IN; k0 += PT_KT) {
        float4 a = *(const float4*)&xrow[k0];
        float4 b = *(const float4*)&xrow[k0 + 4];
        float4 c = *(const float4*)&xrow[k0 + 8];
        float4 d = *(const float4*)&xrow[k0 + 12];
        xs[0][t] = a.x;  xs[1][t] = a.y;  xs[2][t] = a.z;  xs[3][t] = a.w;
        xs[4][t] = b.x;  xs[5][t] = b.y;  xs[6][t] = b.z;  xs[7][t] = b.w;
        xs[8][t] = c.x;  xs[9][t] = c.y;  xs[10][t] = c.z; xs[11][t] = c.w;
        xs[12][t] = d.x; xs[13][t] = d.y; xs[14][t] = d.z; xs[15][t] = d.w;
        float4 w = (wc < 32) ? *(const float4*)&W1l[(size_t)(k0 + wr) * DIM + wc]
                             : *(const float4*)&W1r[(size_t)(k0 + wr) * DIM + (wc - 32)];
        *(float4*)&ws[wr][wc] = w;
        __syncthreads();
#pragma unroll
        for (int kk = 0; kk < PT_KT; ++kk) {
            float xv[8], wv[8];
            *(float4*)&xv[0] = *(const float4*)&xs[kk][ng * 8];
            *(float4*)&xv[4] = *(const float4*)&xs[kk][ng * 8 + 4];
            *(float4*)&wv[0] = *(const float4*)&ws[kk][cg * 8];
            *(float4*)&wv[4] = *(const float4*)&ws[kk][cg * 8 + 4];
#pragma unroll
            for (int i = 0; i < 8; ++i)
#pragma unroll
                for (int j = 0; j < 8; ++j)
                    acc[i][j] = fmaf(xv[i], wv[j], acc[i][j]);
        }
        __syncthreads();
    }

    bool isP = (cg < 4);
    int c0 = (isP ? cg : cg - 4) * 8;
    int nb = n0 + ng * 8;
#pragma unroll
    for (int i = 0; i < 8; ++i) {
        int n = nb + i;
        if (n < N_NODES) {
            if (isP) {
                H8 p;
#pragma unroll
                for (int j = 0; j < 8; ++j) p.h[j] = (half_t)acc[i][j];
                *(float4*)&P1h[(size_t)n * DIM + c0] = p.f4;
            } else {
                *(float4*)&R1[(size_t)n * DIM + c0]     = *(float4*)&acc[i][0];
                *(float4*)&R1[(size_t)n * DIM + c0 + 4] = *(float4*)&acc[i][4];
            }
        }
    }
}

// ================= gather engine =================
// Wave = 16 node-groups x 4 lanes; lane q owns dims 8q..8q+7 of its node.
__device__ __forceinline__ void gather_node(const int* __restrict__ csr,
                                            const half_t* __restrict__ feat,
                                            int rs, int re, int q8, float acc[8]) {
#pragma unroll
    for (int i = 0; i < 8; ++i) acc[i] = 0.f;
    int e = rs;
    for (; e + 2 <= re; e += 2) {
        int s0 = csr[e];
        int s1 = csr[e + 1];
        H8 u0, u1;
        u0.f4 = *(const float4*)&feat[(size_t)s0 * DIM + q8];
        u1.f4 = *(const float4*)&feat[(size_t)s1 * DIM + q8];
#pragma unroll
        for (int i = 0; i < 8; ++i) acc[i] += (float)u0.h[i] + (float)u1.h[i];
    }
    if (e < re) {
        int s0 = csr[e];
        H8 u0;
        u0.f4 = *(const float4*)&feat[(size_t)s0 * DIM + q8];
#pragma unroll
        for (int i = 0; i < 8; ++i) acc[i] += (float)u0.h[i];
    }
}

// ================= layer-1 aggregate + relu (h in fp16) =================
__global__ __launch_bounds__(256)
void agg1_h_kernel(const int* __restrict__ rowstart,
                   const int* __restrict__ degi,
                   const int* __restrict__ csr,
                   const half_t* __restrict__ P1h,
                   const float* __restrict__ R1,
                   const float* __restrict__ b1,
                   half_t* __restrict__ h) {
    int wave = blockIdx.x * 4 + (threadIdx.x >> 6);
    int lane = threadIdx.x & 63;
    int node = wave * 16 + (lane >> 2);
    if (node >= N_NODES) return;
    int q8 = (lane & 3) * 8;
    int rs = rowstart[node];
    int dg = degi[node];
    float acc[8];
    gather_node(csr, P1h, rs, rs + dg, q8, acc);
    float inv = 1.0f / (float)max(dg, 1);
    float4 r0 = *(const float4*)&R1[(size_t)node * DIM + q8];
    float4 r1 = *(const float4*)&R1[(size_t)node * DIM + q8 + 4];
    float4 bb0 = *(const float4*)&b1[q8];
    float4 bb1 = *(const float4*)&b1[q8 + 4];
    float rb[8] = { r0.x + bb0.x, r0.y + bb0.y, r0.z + bb0.z, r0.w + bb0.w,
                    r1.x + bb1.x, r1.y + bb1.y, r1.z + bb1.z, r1.w + bb1.w };
    H8 o;
#pragma unroll
    for (int i = 0; i < 8; ++i) {
        float v = fmaf(acc[i], inv, rb[i]);
        o.h[i] = (half_t)(v > 0.f ? v : 0.f);
    }
    *(float4*)&h[(size_t)node * DIM + q8] = o.f4;
}

// ================= layer-2 aggregate (a2 in fp16, inv applied) =================
__global__ __launch_bounds__(256)
void agg2_kernel(const int* __restrict__ rowstart,
                 const int* __restrict__ degi,
                 const int* __restrict__ csr,
                 const half_t* __restrict__ h,
                 half_t* __restrict__ a2h) {
    int wave = blockIdx.x * 4 + (threadIdx.x >> 6);
    int lane = threadIdx.x & 63;
    int node = wave * 16 + (lane >> 2);
    if (node >= N_NODES) return;
    int q8 = (lane & 3) * 8;
    int rs = rowstart[node];
    int dg = degi[node];
    float acc[8];
    gather_node(csr, h, rs, rs + dg, q8, acc);
    float inv = 1.0f / (float)max(dg, 1);
    H8 o;
#pragma unroll
    for (int i = 0; i < 8; ++i) o.h[i] = (half_t)(acc[i] * inv);
    *(float4*)&a2h[(size_t)node * DIM + q8] = o.f4;
}

// ================= dense epilogue =================
__global__ __launch_bounds__(256)
void out_dense(const half_t* __restrict__ a2h,
               const half_t* __restrict__ h,
               const float* __restrict__ W2l,
               const float* __restrict__ W2r,
               const float* __restrict__ b2,
               float* __restrict__ out) {
    __shared__ float sWl[DIM * NC];
    __shared__ float sWr[DIM * NC];
    __shared__ float sb[NC];
    for (int i = threadIdx.x; i < DIM * NC; i += 256) {
        sWl[i] = W2l[i];
        sWr[i] = W2r[i];
    }
    if (threadIdx.x < NC) sb[threadIdx.x] = b2[threadIdx.x];
    __syncthreads();

    int n = blockIdx.x * 256 + threadIdx.x;
    if (n >= N_NODES) return;

    float av[32], hv[32];
#pragma unroll
    for (int c = 0; c < 4; ++c) {
        H8 ua, uh;
        ua.f4 = *(const float4*)&a2h[(size_t)n * DIM + c * 8];
        uh.f4 = *(const float4*)&h[(size_t)n * DIM + c * 8];
#pragma unroll
        for (int i = 0; i < 8; ++i) {
            av[c * 8 + i] = (float)ua.h[i];
            hv[c * 8 + i] = (float)uh.h[i];
        }
    }

    float acc[NC];
#pragma unroll
    for (int c = 0; c < NC; ++c) acc[c] = sb[c];
#pragma unroll
    for (int k = 0; k < DIM; ++k) {
        float a = av[k], hh = hv[k];
#pragma unroll
        for (int c = 0; c < NC; ++c)
            acc[c] = fmaf(a, sWl[k * NC + c], fmaf(hh, sWr[k * NC + c], acc[c]));
    }

    float m = acc[0];
#pragma unroll
    for (int c = 1; c < NC; ++c) m = fmaxf(m, acc[c]);
    float s = 0.f;
#pragma unroll
    for (int c = 0; c < NC; ++c) s += __expf(acc[c] - m);
    float lg = m + __logf(s);
    float* orow = out + (size_t)n * NC;
#pragma unroll
    for (int c4 = 0; c4 < NC / 4; ++c4) {
        float4 v = make_float4(acc[c4 * 4] - lg, acc[c4 * 4 + 1] - lg,
                               acc[c4 * 4 + 2] - lg, acc[c4 * 4 + 3] - lg);
        *(float4*)&orow[c4 * 4] = v;
    }
}

// ================= launch =================
extern "C" void kernel_launch(void* const* d_in, const int* in_sizes, int n_in,
                              void* d_out, int out_size, void* d_ws, size_t ws_size,
                              hipStream_t stream) {
    const float* x   = (const float*)d_in[0];
    const int*   ei  = (const int*)d_in[1];   // int32 [2, E]
    const float* W1l = (const float*)d_in[2];
    const float* W1r = (const float*)d_in[3];
    const float* b1  = (const float*)d_in[4];
    const float* W2l = (const float*)d_in[5];
    const float* W2r = (const float*)d_in[6];
    const float* b2  = (const float*)d_in[7];
    float* out = (float*)d_out;

    const int* src = ei;
    const int* dst = ei + N_EDGES;

    char* ws = (char*)d_ws;
    int*    degi     = (int*)ws;      ws += sizeof(int) * 102400;
    int*    rowstart = (int*)ws;      ws += sizeof(int) * 102400;
    int*    cursor   = (int*)ws;      ws += sizeof(int) * 102400;
    int*    partial  = (int*)ws;      ws += sizeof(int) * 512;
    int*    blockoff = (int*)ws;      ws += sizeof(int) * 512;
    int*    csr      = (int*)ws;      ws += sizeof(int) * N_EDGES;
    half_t* P1h      = (half_t*)ws;   ws += sizeof(half_t) * N_NODES * DIM;
    half_t* h        = (half_t*)ws;   ws += sizeof(half_t) * N_NODES * DIM;
    half_t* a2h      = (half_t*)ws;   ws += sizeof(half_t) * N_NODES * DIM;
    float*  R1       = (float*)ws;    ws += sizeof(float) * N_NODES * DIM;

    hipMemsetAsync(degi, 0, sizeof(int) * 102400, stream);

    deg_kernel<<<(N_EDGES + 255) / 256, 256, 0, stream>>>(dst, degi);
    scanA_kernel<<<NBLK, 256, 0, stream>>>(degi, partial);
    scanB_kernel<<<1, 512, 0, stream>>>(partial, blockoff);
    scanC_kernel<<<NBLK, 256, 0, stream>>>(degi, blockoff, rowstart, cursor);
    fill_part_kernel<<<512, 256, 0, stream>>>(src, dst, cursor, csr);

    proj1_tiled<<<(N_NODES + PT_NODES - 1) / PT_NODES, 256, 0, stream>>>(x, W1l, W1r, P1h, R1);

    int gather_blocks = (N_NODES + 63) / 64;
    agg1_h_kernel<<<gather_blocks, 256, 0, stream>>>(rowstart, degi, csr, P1h, R1, b1, h);
    agg2_kernel<<<gather_blocks, 256, 0, stream>>>(rowstart, degi, csr, h, a2h);
    out_dense<<<(N_NODES + 255) / 256, 256, 0, stream>>>(a2h, h, W2l, W2r, b2, out);
}

// Round 7
// 419.106 us; speedup vs baseline: 1.2042x; 1.2042x over previous
//
#include <hip/hip_runtime.h>
#include <hip/hip_bf16.h>
#include <math.h>

#define N_NODES 100000
#define N_EDGES 1600000
#define F_IN 256
#define DIM 32
#define NC 40

#define NBLK 391            // ceil(100000/256)
#define NXCD 8
#define PART_SZ 12500       // N_NODES / NXCD

typedef _Float16 half_t;
union H8 { float4 f4; half_t h[8]; };

// ================= degree =================
__global__ void deg_kernel(const int* __restrict__ dst, int* __restrict__ degi) {
    int i = blockIdx.x * blockDim.x + threadIdx.x;
    if (i < N_EDGES) atomicAdd(&degi[dst[i]], 1);
}

// ================= deterministic prefix scan (3 phases) =================
__device__ __forceinline__ int block_scan_excl(int v, int& tot) {
    int lane = threadIdx.x & 63;
    int wid = threadIdx.x >> 6;
    int s = v;
#pragma unroll
    for (int off = 1; off < 64; off <<= 1) {
        int t = __shfl_up(s, off, 64);
        if (lane >= off) s += t;
    }
    __shared__ int wsum[8];
    if (lane == 63) wsum[wid] = s;
    __syncthreads();
    int nw = (blockDim.x + 63) >> 6;
    int wprev = 0, total = 0;
    for (int i = 0; i < nw; ++i) {
        int t = wsum[i];
        if (i < wid) wprev += t;
        total += t;
    }
    tot = total;
    return wprev + s - v;   // exclusive prefix
}

__global__ void scanA_kernel(const int* __restrict__ degi, int* __restrict__ partial) {
    int i = blockIdx.x * 256 + threadIdx.x;
    int v = (i < N_NODES) ? degi[i] : 0;
    int tot;
    block_scan_excl(v, tot);
    if (threadIdx.x == 0) partial[blockIdx.x] = tot;
}

__global__ void scanB_kernel(int* __restrict__ partial, int* __restrict__ blockoff) {
    int i = threadIdx.x;   // 512 threads
    int v = (i < NBLK) ? partial[i] : 0;
    int tot;
    int ex = block_scan_excl(v, tot);
    if (i < NBLK) blockoff[i] = ex;
}

__global__ void scanC_kernel(const int* __restrict__ degi,
                             const int* __restrict__ blockoff,
                             int* __restrict__ rowstart,
                             int* __restrict__ cursor) {
    int i = blockIdx.x * 256 + threadIdx.x;
    int v = (i < N_NODES) ? degi[i] : 0;
    int tot;
    int ex = block_scan_excl(v, tot) + blockoff[blockIdx.x];
    if (i < N_NODES) {
        rowstart[i] = ex;
        cursor[i] = ex;
    }
}

// ================= XCD-partitioned fill (single pass) =================
// blockIdx%8 -> XCD x (round-robin dispatch heuristic). XCD x owns
// dst in [x*PART_SZ,(x+1)*PART_SZ): its csr window (~800KB) is written by one
// XCD's L2 only, so scattered 4B writes coalesce in L2 before writeback.
// Blocks of one XCD group-stride over ALL edges (each edge seen by 8 groups,
// processed by exactly one).
__global__ __launch_bounds__(256)
void fill_xcd_kernel(const int* __restrict__ src,
                     const int* __restrict__ dst,
                     int* __restrict__ cursor,
                     int* __restrict__ csr) {
    int x = blockIdx.x & (NXCD - 1);              // XCD id
    int gblk = blockIdx.x >> 3;                   // block index within group
    int gsize = gridDim.x >> 3;                   // blocks per group
    int tid = gblk * blockDim.x + threadIdx.x;    // thread id within group
    int stride = gsize * blockDim.x;
    int lo = x * PART_SZ;
    int hi = (x == NXCD - 1) ? N_NODES : lo + PART_SZ;

    const int4* dst4 = (const int4*)dst;
    for (int e4 = tid; e4 < N_EDGES / 4; e4 += stride) {
        int4 d4 = dst4[e4];
        int e = e4 * 4;
#pragma unroll
        for (int c = 0; c < 4; ++c) {
            int d = (c == 0) ? d4.x : (c == 1) ? d4.y : (c == 2) ? d4.z : d4.w;
            if (d >= lo && d < hi) {
                int pos = atomicAdd(&cursor[d], 1);
                csr[pos] = src[e + c];
            }
        }
    }
}

// ================= layer-1 projection (register-tiled GEMM) =================
#define PT_NODES 256
#define PT_KT 16

__global__ __launch_bounds__(256)
void proj1_tiled(const float* __restrict__ x,
                 const float* __restrict__ W1l,
                 const float* __restrict__ W1r,
                 half_t* __restrict__ P1h,
                 float* __restrict__ R1) {
    __shared__ float xs[PT_KT][PT_NODES];  // 16 KB
    __shared__ float ws[PT_KT][64];        // 4 KB
    int t = threadIdx.x;
    int ng = t >> 3;   // 0..31 node group
    int cg = t & 7;    // 0..7 col group
    int n0 = blockIdx.x * PT_NODES;

    float acc[8][8];
#pragma unroll
    for (int i = 0; i < 8; ++i)
#pragma unroll
        for (int j = 0; j < 8; ++j) acc[i][j] = 0.f;

    int ldnode = n0 + t; if (ldnode >= N_NODES) ldnode = N_NODES - 1;
    const float* xrow = x + (size_t)ldnode * F_IN;
    int wr = t >> 4;           // 0..15 (k within tile)
    int wc = (t & 15) * 4;     // 0..60

    for (int k0 = 0; k0 < F_IN; k0 += PT_KT) {
        float4 a = *(const float4*)&xrow[k0];
        float4 b = *(const float4*)&xrow[k0 + 4];
        float4 c = *(const float4*)&xrow[k0 + 8];
        float4 d = *(const float4*)&xrow[k0 + 12];
        xs[0][t] = a.x;  xs[1][t] = a.y;  xs[2][t] = a.z;  xs[3][t] = a.w;
        xs[4][t] = b.x;  xs[5][t] = b.y;  xs[6][t] = b.z;  xs[7][t] = b.w;
        xs[8][t] = c.x;  xs[9][t] = c.y;  xs[10][t] = c.z; xs[11][t] = c.w;
        xs[12][t] = d.x; xs[13][t] = d.y; xs[14][t] = d.z; xs[15][t] = d.w;
        float4 w = (wc < 32) ? *(const float4*)&W1l[(size_t)(k0 + wr) * DIM + wc]
                             : *(const float4*)&W1r[(size_t)(k0 + wr) * DIM + (wc - 32)];
        *(float4*)&ws[wr][wc] = w;
        __syncthreads();
#pragma unroll
        for (int kk = 0; kk < PT_KT; ++kk) {
            float xv[8], wv[8];
            *(float4*)&xv[0] = *(const float4*)&xs[kk][ng * 8];
            *(float4*)&xv[4] = *(const float4*)&xs[kk][ng * 8 + 4];
            *(float4*)&wv[0] = *(const float4*)&ws[kk][cg * 8];
            *(float4*)&wv[4] = *(const float4*)&ws[kk][cg * 8 + 4];
#pragma unroll
            for (int i = 0; i < 8; ++i)
#pragma unroll
                for (int j = 0; j < 8; ++j)
                    acc[i][j] = fmaf(xv[i], wv[j], acc[i][j]);
        }
        __syncthreads();
    }

    bool isP = (cg < 4);
    int c0 = (isP ? cg : cg - 4) * 8;
    int nb = n0 + ng * 8;
#pragma unroll
    for (int i = 0; i < 8; ++i) {
        int n = nb + i;
        if (n < N_NODES) {
            if (isP) {
                H8 p;
#pragma unroll
                for (int j = 0; j < 8; ++j) p.h[j] = (half_t)acc[i][j];
                *(float4*)&P1h[(size_t)n * DIM + c0] = p.f4;
            } else {
                *(float4*)&R1[(size_t)n * DIM + c0]     = *(float4*)&acc[i][0];
                *(float4*)&R1[(size_t)n * DIM + c0 + 4] = *(float4*)&acc[i][4];
            }
        }
    }
}

// ================= gather engine =================
// Wave = 16 node-groups x 4 lanes; lane q owns dims 8q..8q+7 of its node.
__device__ __forceinline__ void gather_node(const int* __restrict__ csr,
                                            const half_t* __restrict__ feat,
                                            int rs, int re, int q8, float acc[8]) {
#pragma unroll
    for (int i = 0; i < 8; ++i) acc[i] = 0.f;
    int e = rs;
    for (; e + 2 <= re; e += 2) {
        int s0 = csr[e];
        int s1 = csr[e + 1];
        H8 u0, u1;
        u0.f4 = *(const float4*)&feat[(size_t)s0 * DIM + q8];
        u1.f4 = *(const float4*)&feat[(size_t)s1 * DIM + q8];
#pragma unroll
        for (int i = 0; i < 8; ++i) acc[i] += (float)u0.h[i] + (float)u1.h[i];
    }
    if (e < re) {
        int s0 = csr[e];
        H8 u0;
        u0.f4 = *(const float4*)&feat[(size_t)s0 * DIM + q8];
#pragma unroll
        for (int i = 0; i < 8; ++i) acc[i] += (float)u0.h[i];
    }
}

// ================= layer-1 aggregate + relu (h in fp16) =================
__global__ __launch_bounds__(256)
void agg1_h_kernel(const int* __restrict__ rowstart,
                   const int* __restrict__ degi,
                   const int* __restrict__ csr,
                   const half_t* __restrict__ P1h,
                   const float* __restrict__ R1,
                   const float* __restrict__ b1,
                   half_t* __restrict__ h) {
    int wave = blockIdx.x * 4 + (threadIdx.x >> 6);
    int lane = threadIdx.x & 63;
    int node = wave * 16 + (lane >> 2);
    if (node >= N_NODES) return;
    int q8 = (lane & 3) * 8;
    int rs = rowstart[node];
    int dg = degi[node];
    float acc[8];
    gather_node(csr, P1h, rs, rs + dg, q8, acc);
    float inv = 1.0f / (float)max(dg, 1);
    float4 r0 = *(const float4*)&R1[(size_t)node * DIM + q8];
    float4 r1 = *(const float4*)&R1[(size_t)node * DIM + q8 + 4];
    float4 bb0 = *(const float4*)&b1[q8];
    float4 bb1 = *(const float4*)&b1[q8 + 4];
    float rb[8] = { r0.x + bb0.x, r0.y + bb0.y, r0.z + bb0.z, r0.w + bb0.w,
                    r1.x + bb1.x, r1.y + bb1.y, r1.z + bb1.z, r1.w + bb1.w };
    H8 o;
#pragma unroll
    for (int i = 0; i < 8; ++i) {
        float v = fmaf(acc[i], inv, rb[i]);
        o.h[i] = (half_t)(v > 0.f ? v : 0.f);
    }
    *(float4*)&h[(size_t)node * DIM + q8] = o.f4;
}

// ================= layer-2 aggregate (a2 in fp16, inv applied) =================
__global__ __launch_bounds__(256)
void agg2_kernel(const int* __restrict__ rowstart,
                 const int* __restrict__ degi,
                 const int* __restrict__ csr,
                 const half_t* __restrict__ h,
                 half_t* __restrict__ a2h) {
    int wave = blockIdx.x * 4 + (threadIdx.x >> 6);
    int lane = threadIdx.x & 63;
    int node = wave * 16 + (lane >> 2);
    if (node >= N_NODES) return;
    int q8 = (lane & 3) * 8;
    int rs = rowstart[node];
    int dg = degi[node];
    float acc[8];
    gather_node(csr, h, rs, rs + dg, q8, acc);
    float inv = 1.0f / (float)max(dg, 1);
    H8 o;
#pragma unroll
    for (int i = 0; i < 8; ++i) o.h[i] = (half_t)(acc[i] * inv);
    *(float4*)&a2h[(size_t)node * DIM + q8] = o.f4;
}

// ================= dense epilogue =================
__global__ __launch_bounds__(256)
void out_dense(const half_t* __restrict__ a2h,
               const half_t* __restrict__ h,
               const float* __restrict__ W2l,
               const float* __restrict__ W2r,
               const float* __restrict__ b2,
               float* __restrict__ out) {
    __shared__ float sWl[DIM * NC];
    __shared__ float sWr[DIM * NC];
    __shared__ float sb[NC];
    for (int i = threadIdx.x; i < DIM * NC; i += 256) {
        sWl[i] = W2l[i];
        sWr[i] = W2r[i];
    }
    if (threadIdx.x < NC) sb[threadIdx.x] = b2[threadIdx.x];
    __syncthreads();

    int n = blockIdx.x * 256 + threadIdx.x;
    if (n >= N_NODES) return;

    float av[32], hv[32];
#pragma unroll
    for (int c = 0; c < 4; ++c) {
        H8 ua, uh;
        ua.f4 = *(const float4*)&a2h[(size_t)n * DIM + c * 8];
        uh.f4 = *(const float4*)&h[(size_t)n * DIM + c * 8];
#pragma unroll
        for (int i = 0; i < 8; ++i) {
            av[c * 8 + i] = (float)ua.h[i];
            hv[c * 8 + i] = (float)uh.h[i];
        }
    }

    float acc[NC];
#pragma unroll
    for (int c = 0; c < NC; ++c) acc[c] = sb[c];
#pragma unroll
    for (int k = 0; k < DIM; ++k) {
        float a = av[k], hh = hv[k];
#pragma unroll
        for (int c = 0; c < NC; ++c)
            acc[c] = fmaf(a, sWl[k * NC + c], fmaf(hh, sWr[k * NC + c], acc[c]));
    }

    float m = acc[0];
#pragma unroll
    for (int c = 1; c < NC; ++c) m = fmaxf(m, acc[c]);
    float s = 0.f;
#pragma unroll
    for (int c = 0; c < NC; ++c) s += __expf(acc[c] - m);
    float lg = m + __logf(s);
    float* orow = out + (size_t)n * NC;
#pragma unroll
    for (int c4 = 0; c4 < NC / 4; ++c4) {
        float4 v = make_float4(acc[c4 * 4] - lg, acc[c4 * 4 + 1] - lg,
                               acc[c4 * 4 + 2] - lg, acc[c4 * 4 + 3] - lg);
        *(float4*)&orow[c4 * 4] = v;
    }
}

// ================= launch =================
extern "C" void kernel_launch(void* const* d_in, const int* in_sizes, int n_in,
                              void* d_out, int out_size, void* d_ws, size_t ws_size,
                              hipStream_t stream) {
    const float* x   = (const float*)d_in[0];
    const int*   ei  = (const int*)d_in[1];   // int32 [2, E]
    const float* W1l = (const float*)d_in[2];
    const float* W1r = (const float*)d_in[3];
    const float* b1  = (const float*)d_in[4];
    const float* W2l = (const float*)d_in[5];
    const float* W2r = (const float*)d_in[6];
    const float* b2  = (const float*)d_in[7];
    float* out = (float*)d_out;

    const int* src = ei;
    const int* dst = ei + N_EDGES;

    char* ws = (char*)d_ws;
    int*    degi     = (int*)ws;      ws += sizeof(int) * 102400;
    int*    rowstart = (int*)ws;      ws += sizeof(int) * 102400;
    int*    cursor   = (int*)ws;      ws += sizeof(int) * 102400;
    int*    partial  = (int*)ws;      ws += sizeof(int) * 512;
    int*    blockoff = (int*)ws;      ws += sizeof(int) * 512;
    int*    csr      = (int*)ws;      ws += sizeof(int) * N_EDGES;
    half_t* P1h      = (half_t*)ws;   ws += sizeof(half_t) * N_NODES * DIM;
    half_t* h        = (half_t*)ws;   ws += sizeof(half_t) * N_NODES * DIM;
    half_t* a2h      = (half_t*)ws;   ws += sizeof(half_t) * N_NODES * DIM;
    float*  R1       = (float*)ws;    ws += sizeof(float) * N_NODES * DIM;

    hipMemsetAsync(degi, 0, sizeof(int) * 102400, stream);

    deg_kernel<<<(N_EDGES + 255) / 256, 256, 0, stream>>>(dst, degi);
    scanA_kernel<<<NBLK, 256, 0, stream>>>(degi, partial);
    scanB_kernel<<<1, 512, 0, stream>>>(partial, blockoff);
    scanC_kernel<<<NBLK, 256, 0, stream>>>(degi, blockoff, rowstart, cursor);
    fill_xcd_kernel<<<2048, 256, 0, stream>>>(src, dst, cursor, csr);

    proj1_tiled<<<(N_NODES + PT_NODES - 1) / PT_NODES, 256, 0, stream>>>(x, W1l, W1r, P1h, R1);

    int gather_blocks = (N_NODES + 63) / 64;
    agg1_h_kernel<<<gather_blocks, 256, 0, stream>>>(rowstart, degi, csr, P1h, R1, b1, h);
    agg2_kernel<<<gather_blocks, 256, 0, stream>>>(rowstart, degi, csr, h, a2h);
    out_dense<<<(N_NODES + 255) / 256, 256, 0, stream>>>(a2h, h, W2l, W2r, b2, out);
}

// Round 8
// 410.623 us; speedup vs baseline: 1.2291x; 1.0207x over previous
//
#include <hip/hip_runtime.h>
#include <hip/hip_bf16.h>
#include <math.h>

#define N_NODES 100000
#define N_EDGES 1600000
#define F_IN 256
#define DIM 32
#define NC 40

#define NBLK 391            // ceil(100000/256)
#define NXCD 8
#define PART_SZ 12500       // N_NODES / NXCD

typedef _Float16 half_t;
union H8 { float4 f4; half_t h[8]; };

// ================= degree =================
__global__ void deg_kernel(const int* __restrict__ dst, int* __restrict__ degi) {
    int i = blockIdx.x * blockDim.x + threadIdx.x;
    if (i < N_EDGES) atomicAdd(&degi[dst[i]], 1);
}

// ================= deterministic prefix scan (3 phases) =================
__device__ __forceinline__ int block_scan_excl(int v, int& tot) {
    int lane = threadIdx.x & 63;
    int wid = threadIdx.x >> 6;
    int s = v;
#pragma unroll
    for (int off = 1; off < 64; off <<= 1) {
        int t = __shfl_up(s, off, 64);
        if (lane >= off) s += t;
    }
    __shared__ int wsum[8];
    if (lane == 63) wsum[wid] = s;
    __syncthreads();
    int nw = (blockDim.x + 63) >> 6;
    int wprev = 0, total = 0;
    for (int i = 0; i < nw; ++i) {
        int t = wsum[i];
        if (i < wid) wprev += t;
        total += t;
    }
    tot = total;
    return wprev + s - v;   // exclusive prefix
}

__global__ void scanA_kernel(const int* __restrict__ degi, int* __restrict__ partial) {
    int i = blockIdx.x * 256 + threadIdx.x;
    int v = (i < N_NODES) ? degi[i] : 0;
    int tot;
    block_scan_excl(v, tot);
    if (threadIdx.x == 0) partial[blockIdx.x] = tot;
}

__global__ void scanB_kernel(int* __restrict__ partial, int* __restrict__ blockoff) {
    int i = threadIdx.x;   // 512 threads
    int v = (i < NBLK) ? partial[i] : 0;
    int tot;
    int ex = block_scan_excl(v, tot);
    if (i < NBLK) blockoff[i] = ex;
}

__global__ void scanC_kernel(const int* __restrict__ degi,
                             const int* __restrict__ blockoff,
                             int* __restrict__ rowstart,
                             int* __restrict__ cursor) {
    int i = blockIdx.x * 256 + threadIdx.x;
    int v = (i < N_NODES) ? degi[i] : 0;
    int tot;
    int ex = block_scan_excl(v, tot) + blockoff[blockIdx.x];
    if (i < N_NODES) {
        rowstart[i] = ex;
        cursor[i] = ex;
    }
}

// ================= XCD-partitioned fill (single pass) =================
__global__ __launch_bounds__(256)
void fill_xcd_kernel(const int* __restrict__ src,
                     const int* __restrict__ dst,
                     int* __restrict__ cursor,
                     int* __restrict__ csr) {
    int x = blockIdx.x & (NXCD - 1);              // XCD id
    int gblk = blockIdx.x >> 3;                   // block index within group
    int gsize = gridDim.x >> 3;                   // blocks per group
    int tid = gblk * blockDim.x + threadIdx.x;    // thread id within group
    int stride = gsize * blockDim.x;
    int lo = x * PART_SZ;
    int hi = (x == NXCD - 1) ? N_NODES : lo + PART_SZ;

    const int4* dst4 = (const int4*)dst;
    for (int e4 = tid; e4 < N_EDGES / 4; e4 += stride) {
        int4 d4 = dst4[e4];
        int e = e4 * 4;
#pragma unroll
        for (int c = 0; c < 4; ++c) {
            int d = (c == 0) ? d4.x : (c == 1) ? d4.y : (c == 2) ? d4.z : d4.w;
            if (d >= lo && d < hi) {
                int pos = atomicAdd(&cursor[d], 1);
                csr[pos] = src[e + c];
            }
        }
    }
}

// ================= layer-1 projection (register-tiled GEMM) =================
// 128-node x 64-col tile per block -> grid 782 (~3 blocks/CU) for occupancy.
// Thread: 4 nodes x 8 cols outer-product from LDS.
#define PT_NODES 128
#define PT_KT 16

__global__ __launch_bounds__(256)
void proj1_tiled(const float* __restrict__ x,
                 const float* __restrict__ W1l,
                 const float* __restrict__ W1r,
                 half_t* __restrict__ P1h,
                 float* __restrict__ R1) {
    __shared__ float xs[PT_KT][PT_NODES];  // 8 KB
    __shared__ float ws[PT_KT][64];        // 4 KB
    int t = threadIdx.x;
    int ng = t >> 3;   // 0..31 node group (4 nodes each)
    int cg = t & 7;    // 0..7 col group (8 cols each)
    int n0 = blockIdx.x * PT_NODES;

    float acc[4][8];
#pragma unroll
    for (int i = 0; i < 4; ++i)
#pragma unroll
        for (int j = 0; j < 8; ++j) acc[i][j] = 0.f;

    // staging map: thread = (node ln 0..127, k-half kh {0,8}); 8 floats/thread
    int ln = t & 127;
    int kh = (t >> 7) * 8;
    int ldnode = n0 + ln; if (ldnode >= N_NODES) ldnode = N_NODES - 1;
    const float* xrow = x + (size_t)ldnode * F_IN + kh;
    int wr = t >> 4;           // 0..15 (k within tile)
    int wc = (t & 15) * 4;     // 0..60

    for (int k0 = 0; k0 < F_IN; k0 += PT_KT) {
        float4 a = *(const float4*)&xrow[k0];
        float4 b = *(const float4*)&xrow[k0 + 4];
        xs[kh + 0][ln] = a.x; xs[kh + 1][ln] = a.y;
        xs[kh + 2][ln] = a.z; xs[kh + 3][ln] = a.w;
        xs[kh + 4][ln] = b.x; xs[kh + 5][ln] = b.y;
        xs[kh + 6][ln] = b.z; xs[kh + 7][ln] = b.w;
        float4 w = (wc < 32) ? *(const float4*)&W1l[(size_t)(k0 + wr) * DIM + wc]
                             : *(const float4*)&W1r[(size_t)(k0 + wr) * DIM + (wc - 32)];
        *(float4*)&ws[wr][wc] = w;
        __syncthreads();
#pragma unroll
        for (int kk = 0; kk < PT_KT; ++kk) {
            float xv[4], wv[8];
            *(float4*)&xv[0] = *(const float4*)&xs[kk][ng * 4];
            *(float4*)&wv[0] = *(const float4*)&ws[kk][cg * 8];
            *(float4*)&wv[4] = *(const float4*)&ws[kk][cg * 8 + 4];
#pragma unroll
            for (int i = 0; i < 4; ++i)
#pragma unroll
                for (int j = 0; j < 8; ++j)
                    acc[i][j] = fmaf(xv[i], wv[j], acc[i][j]);
        }
        __syncthreads();
    }

    bool isP = (cg < 4);
    int c0 = (isP ? cg : cg - 4) * 8;
    int nb = n0 + ng * 4;
#pragma unroll
    for (int i = 0; i < 4; ++i) {
        int n = nb + i;
        if (n < N_NODES) {
            if (isP) {
                H8 p;
#pragma unroll
                for (int j = 0; j < 8; ++j) p.h[j] = (half_t)acc[i][j];
                *(float4*)&P1h[(size_t)n * DIM + c0] = p.f4;
            } else {
                *(float4*)&R1[(size_t)n * DIM + c0]     = *(float4*)&acc[i][0];
                *(float4*)&R1[(size_t)n * DIM + c0 + 4] = *(float4*)&acc[i][4];
            }
        }
    }
}

// ================= gather engine =================
__device__ __forceinline__ void gather_node(const int* __restrict__ csr,
                                            const half_t* __restrict__ feat,
                                            int rs, int re, int q8, float acc[8]) {
#pragma unroll
    for (int i = 0; i < 8; ++i) acc[i] = 0.f;
    int e = rs;
    for (; e + 2 <= re; e += 2) {
        int s0 = csr[e];
        int s1 = csr[e + 1];
        H8 u0, u1;
        u0.f4 = *(const float4*)&feat[(size_t)s0 * DIM + q8];
        u1.f4 = *(const float4*)&feat[(size_t)s1 * DIM + q8];
#pragma unroll
        for (int i = 0; i < 8; ++i) acc[i] += (float)u0.h[i] + (float)u1.h[i];
    }
    if (e < re) {
        int s0 = csr[e];
        H8 u0;
        u0.f4 = *(const float4*)&feat[(size_t)s0 * DIM + q8];
#pragma unroll
        for (int i = 0; i < 8; ++i) acc[i] += (float)u0.h[i];
    }
}

// ================= layer-1 aggregate + relu (h in fp16) =================
__global__ __launch_bounds__(256)
void agg1_h_kernel(const int* __restrict__ rowstart,
                   const int* __restrict__ degi,
                   const int* __restrict__ csr,
                   const half_t* __restrict__ P1h,
                   const float* __restrict__ R1,
                   const float* __restrict__ b1,
                   half_t* __restrict__ h) {
    int wave = blockIdx.x * 4 + (threadIdx.x >> 6);
    int lane = threadIdx.x & 63;
    int node = wave * 16 + (lane >> 2);
    if (node >= N_NODES) return;
    int q8 = (lane & 3) * 8;
    int rs = rowstart[node];
    int dg = degi[node];
    float acc[8];
    gather_node(csr, P1h, rs, rs + dg, q8, acc);
    float inv = 1.0f / (float)max(dg, 1);
    float4 r0 = *(const float4*)&R1[(size_t)node * DIM + q8];
    float4 r1 = *(const float4*)&R1[(size_t)node * DIM + q8 + 4];
    float4 bb0 = *(const float4*)&b1[q8];
    float4 bb1 = *(const float4*)&b1[q8 + 4];
    float rb[8] = { r0.x + bb0.x, r0.y + bb0.y, r0.z + bb0.z, r0.w + bb0.w,
                    r1.x + bb1.x, r1.y + bb1.y, r1.z + bb1.z, r1.w + bb1.w };
    H8 o;
#pragma unroll
    for (int i = 0; i < 8; ++i) {
        float v = fmaf(acc[i], inv, rb[i]);
        o.h[i] = (half_t)(v > 0.f ? v : 0.f);
    }
    *(float4*)&h[(size_t)node * DIM + q8] = o.f4;
}

// ================= layer-2 aggregate (a2 in fp16, inv applied) =================
__global__ __launch_bounds__(256)
void agg2_kernel(const int* __restrict__ rowstart,
                 const int* __restrict__ degi,
                 const int* __restrict__ csr,
                 const half_t* __restrict__ h,
                 half_t* __restrict__ a2h) {
    int wave = blockIdx.x * 4 + (threadIdx.x >> 6);
    int lane = threadIdx.x & 63;
    int node = wave * 16 + (lane >> 2);
    if (node >= N_NODES) return;
    int q8 = (lane & 3) * 8;
    int rs = rowstart[node];
    int dg = degi[node];
    float acc[8];
    gather_node(csr, h, rs, rs + dg, q8, acc);
    float inv = 1.0f / (float)max(dg, 1);
    H8 o;
#pragma unroll
    for (int i = 0; i < 8; ++i) o.h[i] = (half_t)(acc[i] * inv);
    *(float4*)&a2h[(size_t)node * DIM + q8] = o.f4;
}

// ================= dense epilogue =================
__global__ __launch_bounds__(256)
void out_dense(const half_t* __restrict__ a2h,
               const half_t* __restrict__ h,
               const float* __restrict__ W2l,
               const float* __restrict__ W2r,
               const float* __restrict__ b2,
               float* __restrict__ out) {
    __shared__ float sWl[DIM * NC];
    __shared__ float sWr[DIM * NC];
    __shared__ float sb[NC];
    for (int i = threadIdx.x; i < DIM * NC; i += 256) {
        sWl[i] = W2l[i];
        sWr[i] = W2r[i];
    }
    if (threadIdx.x < NC) sb[threadIdx.x] = b2[threadIdx.x];
    __syncthreads();

    int n = blockIdx.x * 256 + threadIdx.x;
    if (n >= N_NODES) return;

    float av[32], hv[32];
#pragma unroll
    for (int c = 0; c < 4; ++c) {
        H8 ua, uh;
        ua.f4 = *(const float4*)&a2h[(size_t)n * DIM + c * 8];
        uh.f4 = *(const float4*)&h[(size_t)n * DIM + c * 8];
#pragma unroll
        for (int i = 0; i < 8; ++i) {
            av[c * 8 + i] = (float)ua.h[i];
            hv[c * 8 + i] = (float)uh.h[i];
        }
    }

    float acc[NC];
#pragma unroll
    for (int c = 0; c < NC; ++c) acc[c] = sb[c];
#pragma unroll
    for (int k = 0; k < DIM; ++k) {
        float a = av[k], hh = hv[k];
#pragma unroll
        for (int c = 0; c < NC; ++c)
            acc[c] = fmaf(a, sWl[k * NC + c], fmaf(hh, sWr[k * NC + c], acc[c]));
    }

    float m = acc[0];
#pragma unroll
    for (int c = 1; c < NC; ++c) m = fmaxf(m, acc[c]);
    float s = 0.f;
#pragma unroll
    for (int c = 0; c < NC; ++c) s += __expf(acc[c] - m);
    float lg = m + __logf(s);
    float* orow = out + (size_t)n * NC;
#pragma unroll
    for (int c4 = 0; c4 < NC / 4; ++c4) {
        float4 v = make_float4(acc[c4 * 4] - lg, acc[c4 * 4 + 1] - lg,
                               acc[c4 * 4 + 2] - lg, acc[c4 * 4 + 3] - lg);
        *(float4*)&orow[c4 * 4] = v;
    }
}

// ================= launch =================
extern "C" void kernel_launch(void* const* d_in, const int* in_sizes, int n_in,
                              void* d_out, int out_size, void* d_ws, size_t ws_size,
                              hipStream_t stream) {
    const float* x   = (const float*)d_in[0];
    const int*   ei  = (const int*)d_in[1];   // int32 [2, E]
    const float* W1l = (const float*)d_in[2];
    const float* W1r = (const float*)d_in[3];
    const float* b1  = (const float*)d_in[4];
    const float* W2l = (const float*)d_in[5];
    const float* W2r = (const float*)d_in[6];
    const float* b2  = (const float*)d_in[7];
    float* out = (float*)d_out;

    const int* src = ei;
    const int* dst = ei + N_EDGES;

    char* ws = (char*)d_ws;
    int*    degi     = (int*)ws;      ws += sizeof(int) * 102400;
    int*    rowstart = (int*)ws;      ws += sizeof(int) * 102400;
    int*    cursor   = (int*)ws;      ws += sizeof(int) * 102400;
    int*    partial  = (int*)ws;      ws += sizeof(int) * 512;
    int*    blockoff = (int*)ws;      ws += sizeof(int) * 512;
    int*    csr      = (int*)ws;      ws += sizeof(int) * N_EDGES;
    half_t* P1h      = (half_t*)ws;   ws += sizeof(half_t) * N_NODES * DIM;
    half_t* h        = (half_t*)ws;   ws += sizeof(half_t) * N_NODES * DIM;
    half_t* a2h      = (half_t*)ws;   ws += sizeof(half_t) * N_NODES * DIM;
    float*  R1       = (float*)ws;    ws += sizeof(float) * N_NODES * DIM;

    hipMemsetAsync(degi, 0, sizeof(int) * 102400, stream);

    deg_kernel<<<(N_EDGES + 255) / 256, 256, 0, stream>>>(dst, degi);
    scanA_kernel<<<NBLK, 256, 0, stream>>>(degi, partial);
    scanB_kernel<<<1, 512, 0, stream>>>(partial, blockoff);
    scanC_kernel<<<NBLK, 256, 0, stream>>>(degi, blockoff, rowstart, cursor);
    fill_xcd_kernel<<<2048, 256, 0, stream>>>(src, dst, cursor, csr);

    proj1_tiled<<<(N_NODES + PT_NODES - 1) / PT_NODES, 256, 0, stream>>>(x, W1l, W1r, P1h, R1);

    int gather_blocks = (N_NODES + 63) / 64;
    agg1_h_kernel<<<gather_blocks, 256, 0, stream>>>(rowstart, degi, csr, P1h, R1, b1, h);
    agg2_kernel<<<gather_blocks, 256, 0, stream>>>(rowstart, degi, csr, h, a2h);
    out_dense<<<(N_NODES + 255) / 256, 256, 0, stream>>>(a2h, h, W2l, W2r, b2, out);
}